// Round 3
// baseline (334.123 us; speedup 1.0000x reference)
//
#include <hip/hip_runtime.h>

// SupProtoConLoss on MI355X — round 3.
// Round-2 post-mortem: double-buffer raised VGPR 104->136 (4->3 blocks/CU) and
// regressed 64%; inter-block overlap (m114) is the latency-hiding mechanism
// here, so occupancy > pipelining. Quad-only swizzle was a provable no-op
// (conflict counter bit-identical).
// Round 3 = round-1 skeleton (2D grid, single buffer, 2-barrier) +
//  - BK=64 (8 K-iters): halves the count of barrier-drain stalls.
//  - real XOR swizzle: store k-chunk kc of row r at slot kc^(r&7) (8 chunks/row)
//    -> ds_read_b128 bank groups (h*4+quad)^(c16&7) are balanced 8x8 (~free).
//  - round-2's merged LDS-atomic epilogue (WRITE 20->4 MB), lean registers.
//  - __launch_bounds__(256,4) pins VGPR<=128 -> 4 blocks/CU.

#define NROW 8192
#define DDIM 512
#define NCLS 100

typedef float f32x4 __attribute__((ext_vector_type(4)));
typedef short s16x8 __attribute__((ext_vector_type(8)));

#define GLOBAL_AS __attribute__((address_space(1)))
#define LDS_AS __attribute__((address_space(3)))

__device__ __forceinline__ unsigned short f2bf(float x) {
  unsigned int u = __builtin_bit_cast(unsigned int, x);
  u += 0x7FFFu + ((u >> 16) & 1u);  // round-to-nearest-even
  return (unsigned short)(u >> 16);
}

__global__ void k_zero(float* __restrict__ row_pos, float* __restrict__ row_neg,
                       int* __restrict__ cnt) {
  int i = blockIdx.x * blockDim.x + threadIdx.x;
  if (i < NROW) { row_pos[i] = 0.0f; row_neg[i] = 0.0f; }
  if (i < NCLS) cnt[i] = 0;
}

// One wave per row: L2-norm, scale, cast to bf16; label histogram.
__global__ void __launch_bounds__(256) k_prep(
    const float* __restrict__ reps, const int* __restrict__ labels,
    unsigned short* __restrict__ Rb, int* __restrict__ cnt) {
  const int wave = threadIdx.x >> 6;
  const int lane = threadIdx.x & 63;
  const int row = blockIdx.x * 4 + wave;
  const float* r = reps + (size_t)row * DDIM;
  float4 v0 = *(const float4*)(r + lane * 4);
  float4 v1 = *(const float4*)(r + 256 + lane * 4);
  float ss = v0.x * v0.x + v0.y * v0.y + v0.z * v0.z + v0.w * v0.w +
             v1.x * v1.x + v1.y * v1.y + v1.z * v1.z + v1.w * v1.w;
#pragma unroll
  for (int m = 1; m < 64; m <<= 1) ss += __shfl_xor(ss, m);
  const float scale = 1.0f / sqrtf(ss);  // norms ~22.6; 1e-8 clamp unreachable
  ushort4 a, b;
  a.x = f2bf(v0.x * scale); a.y = f2bf(v0.y * scale);
  a.z = f2bf(v0.z * scale); a.w = f2bf(v0.w * scale);
  b.x = f2bf(v1.x * scale); b.y = f2bf(v1.y * scale);
  b.z = f2bf(v1.z * scale); b.w = f2bf(v1.w * scale);
  *(ushort4*)(Rb + (size_t)row * DDIM + lane * 4) = a;
  *(ushort4*)(Rb + (size_t)row * DDIM + 256 + lane * 4) = b;
  if (lane == 0) atomicAdd(&cnt[labels[row]], 1);
}

// 128x128 tile, BK=64 (8 K-iters), 4 waves 2x2, each wave 4x4 of 16x16x32 MFMA.
__global__ void __launch_bounds__(256, 4) k_gemm(
    const unsigned short* __restrict__ Rb, const int* __restrict__ labels,
    float* __restrict__ row_pos, float* __restrict__ row_neg) {
  const int bi = blockIdx.y, bj = blockIdx.x;
  if (bj < bi) return;

  __shared__ __attribute__((aligned(16))) unsigned short As[128 * 64];
  __shared__ __attribute__((aligned(16))) unsigned short Bs[128 * 64];
  __shared__ int labI[128], labJ[128];
  __shared__ float rp[128], rn[128], cp[128], cn[128];

  const int tid = threadIdx.x;
  const int lane = tid & 63;
  const int wave = tid >> 6;
  const int wr = wave >> 1, wc = wave & 1;
  const int quad = lane >> 4, c16 = lane & 15;
  const int i0 = bi * 128, j0 = bj * 128;
  const bool diag = (bi == bj);

  if (tid < 128) {
    labI[tid] = labels[i0 + tid];
    rp[tid] = 0.0f; rn[tid] = 0.0f;
  } else {
    labJ[tid - 128] = labels[j0 + tid - 128];
    cp[tid - 128] = 0.0f; cn[tid - 128] = 0.0f;
  }

  f32x4 acc[4][4];
#pragma unroll
  for (int a = 0; a < 4; ++a)
#pragma unroll
    for (int b = 0; b < 4; ++b) acc[a][b] = (f32x4)0.0f;

  for (int it = 0; it < 8; ++it) {
    __syncthreads();  // LDS reuse guard
    // Stage: 1024 16B-chunks per tile. Chunk c: row = c>>3, stored slot-in-row
    // (c&7) holds global k-chunk kc = (c&7)^(row&7)  (XOR swizzle on source;
    // LDS dst of global_load_lds is HW-fixed at base + lane*16).
#pragma unroll
    for (int t2 = 0; t2 < 4; ++t2) {
      const int cb = wave * 64 + t2 * 256;  // wave-uniform chunk base
      const int c = cb + lane;
      const int rrow = c >> 3;
      const int kc = (c & 7) ^ (rrow & 7);
      const unsigned short* srcA =
          Rb + (size_t)(i0 + rrow) * DDIM + it * 64 + kc * 8;
      const unsigned short* srcB =
          Rb + (size_t)(j0 + rrow) * DDIM + it * 64 + kc * 8;
      __builtin_amdgcn_global_load_lds(
          (GLOBAL_AS void*)const_cast<unsigned short*>(srcA),
          (LDS_AS void*)(As + cb * 8), 16, 0, 0);
      __builtin_amdgcn_global_load_lds(
          (GLOBAL_AS void*)const_cast<unsigned short*>(srcB),
          (LDS_AS void*)(Bs + cb * 8), 16, 0, 0);
    }
    __syncthreads();  // vmcnt(0) drain — the one stall per iter (8 total)

    // Two K-halves reuse the same fragment registers (keeps VGPR <= 128).
#pragma unroll
    for (int h = 0; h < 2; ++h) {
      const int slotk = (h * 4 + quad) ^ (c16 & 7);  // swizzled slot-in-row
      s16x8 af[4], bfr[4];
#pragma unroll
      for (int a = 0; a < 4; ++a) {
        const int row = wr * 64 + a * 16 + c16;
        af[a] = *(const s16x8*)(As + (row * 8 + slotk) * 8);
      }
#pragma unroll
      for (int b = 0; b < 4; ++b) {
        const int row = wc * 64 + b * 16 + c16;
        bfr[b] = *(const s16x8*)(Bs + (row * 8 + slotk) * 8);
      }
#pragma unroll
      for (int a = 0; a < 4; ++a)
#pragma unroll
        for (int b = 0; b < 4; ++b)
          acc[a][b] = __builtin_amdgcn_mfma_f32_16x16x32_bf16(af[a], bfr[b],
                                                              acc[a][b], 0, 0, 0);
    }
  }

  // score(shifted by S=10) = 5g - 5 + 1e-7
  const float C0 = -5.0f + 1e-7f;

  float pc[4] = {0, 0, 0, 0}, nc[4] = {0, 0, 0, 0};
#pragma unroll
  for (int a = 0; a < 4; ++a) {
#pragma unroll
    for (int r = 0; r < 4; ++r) {
      const int ri = wr * 64 + a * 16 + quad * 4 + r;
      const int li = labI[ri];
      float ps = 0.0f, ns = 0.0f;
#pragma unroll
      for (int b = 0; b < 4; ++b) {
        const int cw = wc * 64 + b * 16 + c16;
        const bool same = (li == labJ[cw]);
        const float s = fmaf(acc[a][b][r], 5.0f, C0);
        const float e = __expf(s);
        const float sv = (same && (!diag || ri != cw)) ? s : 0.0f;
        const float ev = same ? 0.0f : e;
        ps += sv; ns += ev;
        pc[b] += sv; nc[b] += ev;
      }
      atomicAdd(&rp[ri], ps);   // ds_add_f32, fire-and-forget
      atomicAdd(&rn[ri], ns);
    }
  }
  if (!diag) {
#pragma unroll
    for (int b = 0; b < 4; ++b) {
      const int cw = wc * 64 + b * 16 + c16;
      atomicAdd(&cp[cw], pc[b]);
      atomicAdd(&cn[cw], nc[b]);
    }
  }

  __syncthreads();
  if (tid < 128) {
    atomicAdd(&row_pos[i0 + tid], rp[tid]);
    atomicAdd(&row_neg[i0 + tid], rn[tid]);
  } else if (!diag) {
    atomicAdd(&row_pos[j0 + tid - 128], cp[tid - 128]);
    atomicAdd(&row_neg[j0 + tid - 128], cn[tid - 128]);
  }
}

__global__ void __launch_bounds__(512) k_final(
    const float* __restrict__ row_pos, const float* __restrict__ row_neg,
    const int* __restrict__ labels, const int* __restrict__ cnt,
    float* __restrict__ out) {
  __shared__ float ssum[8];
  __shared__ float scnt[8];
  const int tid = threadIdx.x;
  float lsum = 0.0f, lcnt = 0.0f;
  for (int i = tid; i < NROW; i += 512) {
    const float c = (float)(cnt[labels[i]] - 1);
    const float pos = row_pos[i] / (c + 1e-8f);
    const float loss = -pos + logf(row_neg[i] + 1e-8f);
    if (loss > 0.0f) { lsum += loss; lcnt += 1.0f; }
  }
#pragma unroll
  for (int m = 1; m < 64; m <<= 1) {
    lsum += __shfl_xor(lsum, m);
    lcnt += __shfl_xor(lcnt, m);
  }
  if ((tid & 63) == 0) { ssum[tid >> 6] = lsum; scnt[tid >> 6] = lcnt; }
  __syncthreads();
  if (tid == 0) {
    float S = 0.0f, C = 0.0f;
#pragma unroll
    for (int w = 0; w < 8; ++w) { S += ssum[w]; C += scnt[w]; }
    out[0] = S / (C + 1e-8f);
  }
}

extern "C" void kernel_launch(void* const* d_in, const int* in_sizes, int n_in,
                              void* d_out, int out_size, void* d_ws, size_t ws_size,
                              hipStream_t stream) {
  const float* reps = (const float*)d_in[0];
  const int* labels = (const int*)d_in[1];
  float* out = (float*)d_out;
  char* ws = (char*)d_ws;
  // ws layout: Rb (bf16 normalized reps, 8 MiB) | row_pos | row_neg | cnt
  unsigned short* Rb = (unsigned short*)ws;
  float* row_pos = (float*)(ws + (size_t)NROW * DDIM * 2);
  float* row_neg = row_pos + NROW;
  int* cnt = (int*)(row_neg + NROW);

  k_zero<<<32, 256, 0, stream>>>(row_pos, row_neg, cnt);
  k_prep<<<NROW / 4, 256, 0, stream>>>(reps, labels, Rb, cnt);
  dim3 grid(64, 64);
  k_gemm<<<grid, 256, 0, stream>>>(Rb, labels, row_pos, row_neg);
  k_final<<<1, 512, 0, stream>>>(row_pos, row_neg, labels, cnt, out);
  (void)in_sizes; (void)n_in; (void)out_size; (void)ws_size;
}

// Round 4
// 316.342 us; speedup vs baseline: 1.0562x; 1.0562x over previous
//
#include <hip/hip_runtime.h>

// SupProtoConLoss on MI355X — round 4.
// R3 post-mortem: swizzle fixed conflicts to 0, gained nothing (they were
// 2-way/near-free). launch_bounds(256,4) caused scratch spills (VGPR 64+64AGPR,
// WRITE_SIZE 4->30MB) -> both pipes idle. R1's real stall: B-tile staging has
// no XCD-L2 locality (each XCD's 4MiB L2 sees all 8MiB of Rb) -> ~500MB served
// from L3/HBM at full latency, ~250k stall cyc/CU.
// Round 4 = R1 K-loop (BK=32, single buffer, no reg pin) +
//  - XCD-pinned 8x8 supertiles of 128x128 cells: A+B set = 2MiB < 4MiB XCD L2;
//    blk&7 -> XCD heuristic, each supertile's 64 blocks stay on one XCD.
//  - cheap LDS-atomic epilogue (proven -10pts VALUBusy in R2/R3).
//  - k_zero folded into hipMemsetAsync (contiguous scratch).

#define NROW 8192
#define DDIM 512
#define NCLS 100

typedef float f32x4 __attribute__((ext_vector_type(4)));
typedef short s16x8 __attribute__((ext_vector_type(8)));

#define GLOBAL_AS __attribute__((address_space(1)))
#define LDS_AS __attribute__((address_space(3)))

__device__ __forceinline__ unsigned short f2bf(float x) {
  unsigned int u = __builtin_bit_cast(unsigned int, x);
  u += 0x7FFFu + ((u >> 16) & 1u);  // round-to-nearest-even
  return (unsigned short)(u >> 16);
}

// One wave per row: L2-norm, scale, cast to bf16; label histogram.
__global__ void __launch_bounds__(256) k_prep(
    const float* __restrict__ reps, const int* __restrict__ labels,
    unsigned short* __restrict__ Rb, int* __restrict__ cnt) {
  const int wave = threadIdx.x >> 6;
  const int lane = threadIdx.x & 63;
  const int row = blockIdx.x * 4 + wave;
  const float* r = reps + (size_t)row * DDIM;
  float4 v0 = *(const float4*)(r + lane * 4);
  float4 v1 = *(const float4*)(r + 256 + lane * 4);
  float ss = v0.x * v0.x + v0.y * v0.y + v0.z * v0.z + v0.w * v0.w +
             v1.x * v1.x + v1.y * v1.y + v1.z * v1.z + v1.w * v1.w;
#pragma unroll
  for (int m = 1; m < 64; m <<= 1) ss += __shfl_xor(ss, m);
  const float scale = 1.0f / sqrtf(ss);  // norms ~22.6; 1e-8 clamp unreachable
  ushort4 a, b;
  a.x = f2bf(v0.x * scale); a.y = f2bf(v0.y * scale);
  a.z = f2bf(v0.z * scale); a.w = f2bf(v0.w * scale);
  b.x = f2bf(v1.x * scale); b.y = f2bf(v1.y * scale);
  b.z = f2bf(v1.z * scale); b.w = f2bf(v1.w * scale);
  *(ushort4*)(Rb + (size_t)row * DDIM + lane * 4) = a;
  *(ushort4*)(Rb + (size_t)row * DDIM + 256 + lane * 4) = b;
  if (lane == 0) atomicAdd(&cnt[labels[row]], 1);
}

// 128x128 tile, BK=32, 4 waves 2x2, each wave 4x4 of 16x16x32 bf16 MFMA.
// Grid: 2560 blocks = 8 XCD slots x 5 supertile rounds x 64 cells.
__global__ void __launch_bounds__(256) k_gemm(
    const unsigned short* __restrict__ Rb, const int* __restrict__ labels,
    float* __restrict__ row_pos, float* __restrict__ row_neg) {
  // --- XCD-pinned supertile decode ---
  // xcd = blk&7 (dispatch heuristic: consecutive blocks round-robin XCDs).
  // Supertile st = round*8 + xcd stays on one XCD for all its 64 cells.
  const int blk = blockIdx.x;
  const int xcd = blk & 7;
  const int q = blk >> 3;
  const int st = (q >> 6) * 8 + xcd;  // supertile id; valid if < 36
  if (st >= 36) return;
  const int c = q & 63;
  int sbi = 0, cum = 0;  // decode st -> (sbi,sbj) in 8x8 upper triangle
  while (cum + (8 - sbi) <= st) { cum += 8 - sbi; ++sbi; }
  const int sbj = sbi + (st - cum);
  const int bi = sbi * 8 + (c >> 3);
  const int bj = sbj * 8 + (c & 7);
  if (bj < bi) return;  // dead cells exist only in diagonal supertiles

  __shared__ __attribute__((aligned(16))) unsigned short As[128 * 32];
  __shared__ __attribute__((aligned(16))) unsigned short Bs[128 * 32];
  __shared__ int labI[128], labJ[128];
  __shared__ float rp[128], rn[128], cp[128], cn[128];

  const int tid = threadIdx.x;
  const int lane = tid & 63;
  const int wave = tid >> 6;
  const int wr = wave >> 1, wc = wave & 1;
  const int quad = lane >> 4, c16 = lane & 15;
  const int i0 = bi * 128, j0 = bj * 128;
  const bool diag = (bi == bj);

  if (tid < 128) {
    labI[tid] = labels[i0 + tid];
    rp[tid] = 0.0f; rn[tid] = 0.0f;
  } else {
    labJ[tid - 128] = labels[j0 + tid - 128];
    cp[tid - 128] = 0.0f; cn[tid - 128] = 0.0f;
  }

  f32x4 acc[4][4];
#pragma unroll
  for (int a = 0; a < 4; ++a)
#pragma unroll
    for (int b = 0; b < 4; ++b) acc[a][b] = (f32x4)0.0f;

  for (int it = 0; it < 16; ++it) {
    const int k0 = it * 32;
    __syncthreads();  // LDS reuse guard
#pragma unroll
    for (int t2 = 0; t2 < 2; ++t2) {
      const int cb = wave * 64 + t2 * 256;  // wave-uniform chunk base
      const int cc = cb + lane;
      const int rrow = cc >> 2;
      const int kc = cc & 3;
      const unsigned short* srcA = Rb + (size_t)(i0 + rrow) * DDIM + k0 + kc * 8;
      const unsigned short* srcB = Rb + (size_t)(j0 + rrow) * DDIM + k0 + kc * 8;
      __builtin_amdgcn_global_load_lds(
          (GLOBAL_AS void*)const_cast<unsigned short*>(srcA),
          (LDS_AS void*)(As + cb * 8), 16, 0, 0);
      __builtin_amdgcn_global_load_lds(
          (GLOBAL_AS void*)const_cast<unsigned short*>(srcB),
          (LDS_AS void*)(Bs + cb * 8), 16, 0, 0);
    }
    __syncthreads();  // vmcnt(0) drain — L2-hit latency after supertile warmup

    s16x8 af[4], bfr[4];
#pragma unroll
    for (int a = 0; a < 4; ++a)
      af[a] = *(const s16x8*)(As + (wr * 64 + a * 16 + c16) * 32 + quad * 8);
#pragma unroll
    for (int b = 0; b < 4; ++b)
      bfr[b] = *(const s16x8*)(Bs + (wc * 64 + b * 16 + c16) * 32 + quad * 8);
#pragma unroll
    for (int a = 0; a < 4; ++a)
#pragma unroll
      for (int b = 0; b < 4; ++b)
        acc[a][b] = __builtin_amdgcn_mfma_f32_16x16x32_bf16(af[a], bfr[b],
                                                            acc[a][b], 0, 0, 0);
  }

  // score(shifted by S=10) = 5g - 5 + 1e-7
  const float C0 = -5.0f + 1e-7f;

  float pc[4] = {0, 0, 0, 0}, nc[4] = {0, 0, 0, 0};
#pragma unroll
  for (int a = 0; a < 4; ++a) {
#pragma unroll
    for (int r = 0; r < 4; ++r) {
      const int ri = wr * 64 + a * 16 + quad * 4 + r;
      const int li = labI[ri];
      float ps = 0.0f, ns = 0.0f;
#pragma unroll
      for (int b = 0; b < 4; ++b) {
        const int cw = wc * 64 + b * 16 + c16;
        const bool same = (li == labJ[cw]);
        const float s = fmaf(acc[a][b][r], 5.0f, C0);
        const float e = __expf(s);
        const float sv = (same && (!diag || ri != cw)) ? s : 0.0f;
        const float ev = same ? 0.0f : e;
        ps += sv; ns += ev;
        pc[b] += sv; nc[b] += ev;
      }
      atomicAdd(&rp[ri], ps);   // ds_add_f32, fire-and-forget
      atomicAdd(&rn[ri], ns);
    }
  }
  if (!diag) {
#pragma unroll
    for (int b = 0; b < 4; ++b) {
      const int cw = wc * 64 + b * 16 + c16;
      atomicAdd(&cp[cw], pc[b]);
      atomicAdd(&cn[cw], nc[b]);
    }
  }

  __syncthreads();
  if (tid < 128) {
    atomicAdd(&row_pos[i0 + tid], rp[tid]);
    atomicAdd(&row_neg[i0 + tid], rn[tid]);
  } else if (!diag) {
    atomicAdd(&row_pos[j0 + tid - 128], cp[tid - 128]);
    atomicAdd(&row_neg[j0 + tid - 128], cn[tid - 128]);
  }
}

__global__ void __launch_bounds__(512) k_final(
    const float* __restrict__ row_pos, const float* __restrict__ row_neg,
    const int* __restrict__ labels, const int* __restrict__ cnt,
    float* __restrict__ out) {
  __shared__ float ssum[8];
  __shared__ float scnt[8];
  const int tid = threadIdx.x;
  float lsum = 0.0f, lcnt = 0.0f;
  for (int i = tid; i < NROW; i += 512) {
    const float c = (float)(cnt[labels[i]] - 1);
    const float pos = row_pos[i] / (c + 1e-8f);
    const float loss = -pos + logf(row_neg[i] + 1e-8f);
    if (loss > 0.0f) { lsum += loss; lcnt += 1.0f; }
  }
#pragma unroll
  for (int m = 1; m < 64; m <<= 1) {
    lsum += __shfl_xor(lsum, m);
    lcnt += __shfl_xor(lcnt, m);
  }
  if ((tid & 63) == 0) { ssum[tid >> 6] = lsum; scnt[tid >> 6] = lcnt; }
  __syncthreads();
  if (tid == 0) {
    float S = 0.0f, C = 0.0f;
#pragma unroll
    for (int w = 0; w < 8; ++w) { S += ssum[w]; C += scnt[w]; }
    out[0] = S / (C + 1e-8f);
  }
}

extern "C" void kernel_launch(void* const* d_in, const int* in_sizes, int n_in,
                              void* d_out, int out_size, void* d_ws, size_t ws_size,
                              hipStream_t stream) {
  const float* reps = (const float*)d_in[0];
  const int* labels = (const int*)d_in[1];
  float* out = (float*)d_out;
  char* ws = (char*)d_ws;
  // ws layout: Rb (bf16 normalized reps, 8 MiB) | row_pos | row_neg | cnt
  unsigned short* Rb = (unsigned short*)ws;
  float* row_pos = (float*)(ws + (size_t)NROW * DDIM * 2);
  float* row_neg = row_pos + NROW;
  int* cnt = (int*)(row_neg + NROW);

  // row_pos | row_neg | cnt are contiguous: one async memset zeroes all three.
  hipMemsetAsync(row_pos, 0, (size_t)(2 * NROW + NCLS) * 4, stream);
  k_prep<<<NROW / 4, 256, 0, stream>>>(reps, labels, Rb, cnt);
  k_gemm<<<2560, 256, 0, stream>>>(Rb, labels, row_pos, row_neg);
  k_final<<<1, 512, 0, stream>>>(row_pos, row_neg, labels, cnt, out);
  (void)in_sizes; (void)n_in; (void)out_size; (void)ws_size;
}

// Round 6
// 224.291 us; speedup vs baseline: 1.4897x; 1.4104x over previous
//
#include <hip/hip_runtime.h>

// SupProtoConLoss on MI355X — round 5b: row-sweep restructure (compile fix:
// __exp2f is not a HIP device intrinsic; use __expf as in R1-R4).
// Cross-round evidence: every LDS-atomic-epilogue round (R2/R3/R4) is ~80us
// slower than R1's shuffle epilogue (same-address ds_add serializes 16-way);
// and the 128x128-cell structure pays per-block fixed costs (cold staging,
// epilogue, 1.3M contended global atomics) amortized over only 16 K-iters.
// Round 5: block = 64-row A-panel (LDS-resident, 64KB, staged ONCE) x 2048-col
// j-slice, sweeping all j. Row sums accumulate in per-lane REGISTERS across
// the sweep -> zero hot-path atomics, one long 128-chunk K-stream per block
// (m97 long-K regime). Costs 2x MFMA (no symmetry) = 33us pipe-busy floor.
// Grid 512 = exactly 2 blocks/CU (LDS 80KB). s=bx&3 pins each XCD to one
// j-slice (B set 2MB < 4MiB XCD L2).

#define NROW 8192
#define DDIM 512
#define NCLS 100
#define PANEL 64
#define JT 256  // cols per j-tile
#define BK 32

typedef float f32x4 __attribute__((ext_vector_type(4)));
typedef short s16x8 __attribute__((ext_vector_type(8)));

#define GLOBAL_AS __attribute__((address_space(1)))
#define LDS_AS __attribute__((address_space(3)))

__device__ __forceinline__ unsigned short f2bf(float x) {
  unsigned int u = __builtin_bit_cast(unsigned int, x);
  u += 0x7FFFu + ((u >> 16) & 1u);  // round-to-nearest-even
  return (unsigned short)(u >> 16);
}

// One wave per row: L2-norm, scale, cast to bf16; label histogram.
__global__ void __launch_bounds__(256) k_prep(
    const float* __restrict__ reps, const int* __restrict__ labels,
    unsigned short* __restrict__ Rb, int* __restrict__ cnt) {
  const int wave = threadIdx.x >> 6;
  const int lane = threadIdx.x & 63;
  const int row = blockIdx.x * 4 + wave;
  const float* r = reps + (size_t)row * DDIM;
  float4 v0 = *(const float4*)(r + lane * 4);
  float4 v1 = *(const float4*)(r + 256 + lane * 4);
  float ss = v0.x * v0.x + v0.y * v0.y + v0.z * v0.z + v0.w * v0.w +
             v1.x * v1.x + v1.y * v1.y + v1.z * v1.z + v1.w * v1.w;
#pragma unroll
  for (int m = 1; m < 64; m <<= 1) ss += __shfl_xor(ss, m);
  const float scale = 1.0f / sqrtf(ss);  // norms ~22.6; 1e-8 clamp unreachable
  ushort4 a, b;
  a.x = f2bf(v0.x * scale); a.y = f2bf(v0.y * scale);
  a.z = f2bf(v0.z * scale); a.w = f2bf(v0.w * scale);
  b.x = f2bf(v1.x * scale); b.y = f2bf(v1.y * scale);
  b.z = f2bf(v1.z * scale); b.w = f2bf(v1.w * scale);
  *(ushort4*)(Rb + (size_t)row * DDIM + lane * 4) = a;
  *(ushort4*)(Rb + (size_t)row * DDIM + 256 + lane * 4) = b;
  if (lane == 0) atomicAdd(&cnt[labels[row]], 1);
}

// Block = 64-row panel (p = bx>>2) x 2048-col slice (s = bx&3).
// 4 waves side-by-side in cols: wave tile = 64 rows x 64 cols = 4a x 4b
// of 16x16x32 MFMA.
__global__ void __launch_bounds__(256) k_row(
    const unsigned short* __restrict__ Rb, const int* __restrict__ labels,
    float* __restrict__ row_pos, float* __restrict__ row_neg) {
  const int bx = blockIdx.x;
  const int p = bx >> 2;   // row panel 0..127
  const int s = bx & 3;    // j slice 0..3 (constant per XCD under %8 dispatch)
  const int i0 = p * PANEL;
  const int j0s = s * 2048;

  __shared__ __attribute__((aligned(16))) unsigned short As[PANEL * DDIM];  // 64 KB
  __shared__ __attribute__((aligned(16))) unsigned short Bs[JT * BK];       // 16 KB

  const int tid = threadIdx.x;
  const int lane = tid & 63;
  const int wave = tid >> 6;
  const int quad = lane >> 4, c16 = lane & 15;

  // ---- Stage A panel once: row-major 64 x 512, one 1KB wave-instr per row.
#pragma unroll
  for (int rr = 0; rr < 16; ++rr) {
    const int row = wave * 16 + rr;  // wave-uniform
    const unsigned short* src = Rb + (size_t)(i0 + row) * DDIM + lane * 8;
    __builtin_amdgcn_global_load_lds(
        (GLOBAL_AS void*)const_cast<unsigned short*>(src),
        (LDS_AS void*)(As + row * DDIM), 16, 0, 0);
  }

  // Per-lane row labels and running row sums (live across the whole sweep).
  int li16[16];
  float ps16[16], ns16[16];
#pragma unroll
  for (int a = 0; a < 4; ++a)
#pragma unroll
    for (int r = 0; r < 4; ++r) {
      li16[a * 4 + r] = labels[i0 + a * 16 + quad * 4 + r];
      ps16[a * 4 + r] = 0.0f;
      ns16[a * 4 + r] = 0.0f;
    }

  const float C0 = -5.0f + 1e-7f;  // s = 5g - 5 + 1e-7 (static shift S=10)

  for (int jt = 0; jt < 8; ++jt) {
    const int j0 = j0s + jt * JT;
    int lj[4], gj[4];
#pragma unroll
    for (int b = 0; b < 4; ++b) {
      gj[b] = j0 + wave * 64 + b * 16 + c16;
      lj[b] = labels[gj[b]];
    }

    f32x4 acc[4][4];
#pragma unroll
    for (int a = 0; a < 4; ++a)
#pragma unroll
      for (int b = 0; b < 4; ++b) acc[a][b] = (f32x4)0.0f;

    for (int ch = 0; ch < 16; ++ch) {
      __syncthreads();  // Bs consumed (also drains A staging before 1st use)
#pragma unroll
      for (int t = 0; t < 4; ++t) {
        const int cb = wave * 64 + t * 256;  // wave-uniform
        const int sl = cb + lane;            // slot: jrow = sl>>2, kc = sl&3
        const unsigned short* src =
            Rb + (size_t)(j0 + (sl >> 2)) * DDIM + ch * 32 + (sl & 3) * 8;
        __builtin_amdgcn_global_load_lds(
            (GLOBAL_AS void*)const_cast<unsigned short*>(src),
            (LDS_AS void*)(Bs + cb * 8), 16, 0, 0);
      }
      __syncthreads();  // Bs ready

      s16x8 af[4], bfr[4];
#pragma unroll
      for (int a = 0; a < 4; ++a)
        af[a] = *(const s16x8*)(As + (a * 16 + c16) * DDIM + ch * 32 + quad * 8);
#pragma unroll
      for (int b = 0; b < 4; ++b)
        bfr[b] = *(const s16x8*)(Bs + (wave * 64 + b * 16 + c16) * BK + quad * 8);
#pragma unroll
      for (int a = 0; a < 4; ++a)
#pragma unroll
        for (int b = 0; b < 4; ++b)
          acc[a][b] = __builtin_amdgcn_mfma_f32_16x16x32_bf16(af[a], bfr[b],
                                                              acc[a][b], 0, 0, 0);
    }

    // Fold this j-tile into register row sums (no atomics, no materialization).
#pragma unroll
    for (int a = 0; a < 4; ++a) {
#pragma unroll
      for (int r = 0; r < 4; ++r) {
        const int gi = i0 + a * 16 + quad * 4 + r;
        const int li = li16[a * 4 + r];
        float ps = 0.0f, ns = 0.0f;
#pragma unroll
        for (int b = 0; b < 4; ++b) {
          const float g = acc[a][b][r];
          const float sv = fmaf(g, 5.0f, C0);
          const float ev = __expf(sv);
          const bool same = (li == lj[b]);
          ps += (same && gi != gj[b]) ? sv : 0.0f;
          ns += same ? 0.0f : ev;
        }
        ps16[a * 4 + r] += ps;
        ns16[a * 4 + r] += ns;
      }
    }
  }

  // ---- Block epilogue: reduce per-lane sums -> 64 rows, 2 atomics each.
  __syncthreads();                 // sweep done; Bs reusable as scratch
  float* rp = (float*)Bs;          // 64 floats
  float* rn = rp + 64;
  if (tid < 128) rp[tid] = 0.0f;   // zeros rp[0..63] and rn[0..63]
  __syncthreads();
#pragma unroll
  for (int a = 0; a < 4; ++a) {
#pragma unroll
    for (int r = 0; r < 4; ++r) {
      float ps = ps16[a * 4 + r], ns = ns16[a * 4 + r];
#pragma unroll
      for (int m = 1; m < 16; m <<= 1) {  // reduce across the 16 c16 lanes
        ps += __shfl_xor(ps, m);
        ns += __shfl_xor(ns, m);
      }
      if (c16 == 0) {  // 4-way wave contention, once per block: trivial
        atomicAdd(&rp[a * 16 + quad * 4 + r], ps);
        atomicAdd(&rn[a * 16 + quad * 4 + r], ns);
      }
    }
  }
  __syncthreads();
  if (tid < 64) {
    atomicAdd(&row_pos[i0 + tid], rp[tid]);   // 8 adds per address chip-wide
    atomicAdd(&row_neg[i0 + tid], rn[tid]);
  }
}

__global__ void __launch_bounds__(512) k_final(
    const float* __restrict__ row_pos, const float* __restrict__ row_neg,
    const int* __restrict__ labels, const int* __restrict__ cnt,
    float* __restrict__ out) {
  __shared__ float ssum[8];
  __shared__ float scnt[8];
  const int tid = threadIdx.x;
  float lsum = 0.0f, lcnt = 0.0f;
  for (int i = tid; i < NROW; i += 512) {
    const float c = (float)(cnt[labels[i]] - 1);
    const float pos = row_pos[i] / (c + 1e-8f);
    const float loss = -pos + logf(row_neg[i] + 1e-8f);
    if (loss > 0.0f) { lsum += loss; lcnt += 1.0f; }
  }
#pragma unroll
  for (int m = 1; m < 64; m <<= 1) {
    lsum += __shfl_xor(lsum, m);
    lcnt += __shfl_xor(lcnt, m);
  }
  if ((tid & 63) == 0) { ssum[tid >> 6] = lsum; scnt[tid >> 6] = lcnt; }
  __syncthreads();
  if (tid == 0) {
    float S = 0.0f, C = 0.0f;
#pragma unroll
    for (int w = 0; w < 8; ++w) { S += ssum[w]; C += scnt[w]; }
    out[0] = S / (C + 1e-8f);
  }
}

extern "C" void kernel_launch(void* const* d_in, const int* in_sizes, int n_in,
                              void* d_out, int out_size, void* d_ws, size_t ws_size,
                              hipStream_t stream) {
  const float* reps = (const float*)d_in[0];
  const int* labels = (const int*)d_in[1];
  float* out = (float*)d_out;
  char* ws = (char*)d_ws;
  // ws layout: Rb (bf16 normalized reps, 8 MiB) | row_pos | row_neg | cnt
  unsigned short* Rb = (unsigned short*)ws;
  float* row_pos = (float*)(ws + (size_t)NROW * DDIM * 2);
  float* row_neg = row_pos + NROW;
  int* cnt = (int*)(row_neg + NROW);

  // row_pos | row_neg | cnt are contiguous: one async memset zeroes all three.
  (void)hipMemsetAsync(row_pos, 0, (size_t)(2 * NROW + NCLS) * 4, stream);
  k_prep<<<NROW / 4, 256, 0, stream>>>(reps, labels, Rb, cnt);
  k_row<<<512, 256, 0, stream>>>(Rb, labels, row_pos, row_neg);
  k_final<<<1, 512, 0, stream>>>(row_pos, row_neg, labels, cnt, out);
  (void)in_sizes; (void)n_in; (void)out_size; (void)ws_size;
}

// Round 7
// 200.787 us; speedup vs baseline: 1.6641x; 1.1171x over previous
//
#include <hip/hip_runtime.h>

// SupProtoConLoss on MI355X — round 7.
// R6 post-mortem: row-sweep structure validated (2x MFMA of R1 in less time,
// zero hot-path atomics), but As row stride 1024B == 0 mod 128 made every
// A-side ds_read_b128 a 16-way bank conflict (SQ_LDS_BANK_CONFLICT 4.26M ->
// 33.5M; +113k cyc/CU ~ 34% of runtime).
// Round 7 (surgical): As becomes chunk-major [16 ch][64 row][32 k] — same
// 64 KB, staged once, global_load_lds-compatible (per instr: 16 rows x 4
// k-chunks = 1 KB contiguous). Frag read addr = ch*4096 + row*64 + quad*16,
// identical to Bs (8-way "m97 baseline" pattern). Nothing else changed.

#define NROW 8192
#define DDIM 512
#define NCLS 100
#define PANEL 64
#define JT 256  // cols per j-tile
#define BK 32

typedef float f32x4 __attribute__((ext_vector_type(4)));
typedef short s16x8 __attribute__((ext_vector_type(8)));

#define GLOBAL_AS __attribute__((address_space(1)))
#define LDS_AS __attribute__((address_space(3)))

__device__ __forceinline__ unsigned short f2bf(float x) {
  unsigned int u = __builtin_bit_cast(unsigned int, x);
  u += 0x7FFFu + ((u >> 16) & 1u);  // round-to-nearest-even
  return (unsigned short)(u >> 16);
}

// One wave per row: L2-norm, scale, cast to bf16; label histogram.
__global__ void __launch_bounds__(256) k_prep(
    const float* __restrict__ reps, const int* __restrict__ labels,
    unsigned short* __restrict__ Rb, int* __restrict__ cnt) {
  const int wave = threadIdx.x >> 6;
  const int lane = threadIdx.x & 63;
  const int row = blockIdx.x * 4 + wave;
  const float* r = reps + (size_t)row * DDIM;
  float4 v0 = *(const float4*)(r + lane * 4);
  float4 v1 = *(const float4*)(r + 256 + lane * 4);
  float ss = v0.x * v0.x + v0.y * v0.y + v0.z * v0.z + v0.w * v0.w +
             v1.x * v1.x + v1.y * v1.y + v1.z * v1.z + v1.w * v1.w;
#pragma unroll
  for (int m = 1; m < 64; m <<= 1) ss += __shfl_xor(ss, m);
  const float scale = 1.0f / sqrtf(ss);  // norms ~22.6; 1e-8 clamp unreachable
  ushort4 a, b;
  a.x = f2bf(v0.x * scale); a.y = f2bf(v0.y * scale);
  a.z = f2bf(v0.z * scale); a.w = f2bf(v0.w * scale);
  b.x = f2bf(v1.x * scale); b.y = f2bf(v1.y * scale);
  b.z = f2bf(v1.z * scale); b.w = f2bf(v1.w * scale);
  *(ushort4*)(Rb + (size_t)row * DDIM + lane * 4) = a;
  *(ushort4*)(Rb + (size_t)row * DDIM + 256 + lane * 4) = b;
  if (lane == 0) atomicAdd(&cnt[labels[row]], 1);
}

// Block = 64-row panel (p = bx>>2) x 2048-col slice (s = bx&3).
// 4 waves side-by-side in cols: wave tile = 64 rows x 64 cols = 4a x 4b
// of 16x16x32 MFMA.
__global__ void __launch_bounds__(256) k_row(
    const unsigned short* __restrict__ Rb, const int* __restrict__ labels,
    float* __restrict__ row_pos, float* __restrict__ row_neg) {
  const int bx = blockIdx.x;
  const int p = bx >> 2;   // row panel 0..127
  const int s = bx & 3;    // j slice 0..3 (constant per XCD under %8 dispatch)
  const int i0 = p * PANEL;
  const int j0s = s * 2048;

  // As chunk-major: [ch][row][k-within-chunk], 64 KB. Row stride 64 B.
  __shared__ __attribute__((aligned(16))) unsigned short As[16][PANEL][BK];
  __shared__ __attribute__((aligned(16))) unsigned short Bs[JT * BK];  // 16 KB

  const int tid = threadIdx.x;
  const int lane = tid & 63;
  const int wave = tid >> 6;
  const int quad = lane >> 4, c16 = lane & 15;

  // ---- Stage A panel once, chunk-major. Instr ii covers chunk ch, rows
  // rg..rg+15 (16 rows x 4 k-chunks = 64 lanes x 16 B, LDS-contiguous).
#pragma unroll
  for (int t = 0; t < 16; ++t) {
    const int ii = wave * 16 + t;        // wave-uniform, 0..63
    const int ch = ii >> 2;
    const int rg = (ii & 3) * 16;
    const unsigned short* src =
        Rb + (size_t)(i0 + rg + (lane >> 2)) * DDIM + ch * BK + (lane & 3) * 8;
    __builtin_amdgcn_global_load_lds(
        (GLOBAL_AS void*)const_cast<unsigned short*>(src),
        (LDS_AS void*)(&As[ch][rg][0]), 16, 0, 0);
  }

  // Per-lane row labels and running row sums (live across the whole sweep).
  int li16[16];
  float ps16[16], ns16[16];
#pragma unroll
  for (int a = 0; a < 4; ++a)
#pragma unroll
    for (int r = 0; r < 4; ++r) {
      li16[a * 4 + r] = labels[i0 + a * 16 + quad * 4 + r];
      ps16[a * 4 + r] = 0.0f;
      ns16[a * 4 + r] = 0.0f;
    }

  const float C0 = -5.0f + 1e-7f;  // s = 5g - 5 + 1e-7 (static shift S=10)

  for (int jt = 0; jt < 8; ++jt) {
    const int j0 = j0s + jt * JT;
    int lj[4], gj[4];
#pragma unroll
    for (int b = 0; b < 4; ++b) {
      gj[b] = j0 + wave * 64 + b * 16 + c16;
      lj[b] = labels[gj[b]];
    }

    f32x4 acc[4][4];
#pragma unroll
    for (int a = 0; a < 4; ++a)
#pragma unroll
      for (int b = 0; b < 4; ++b) acc[a][b] = (f32x4)0.0f;

    for (int ch = 0; ch < 16; ++ch) {
      __syncthreads();  // Bs consumed (also drains A staging before 1st use)
#pragma unroll
      for (int t = 0; t < 4; ++t) {
        const int cb = wave * 64 + t * 256;  // wave-uniform
        const int sl = cb + lane;            // slot: jrow = sl>>2, kc = sl&3
        const unsigned short* src =
            Rb + (size_t)(j0 + (sl >> 2)) * DDIM + ch * BK + (sl & 3) * 8;
        __builtin_amdgcn_global_load_lds(
            (GLOBAL_AS void*)const_cast<unsigned short*>(src),
            (LDS_AS void*)(Bs + cb * 8), 16, 0, 0);
      }
      __syncthreads();  // Bs ready

      s16x8 af[4], bfr[4];
#pragma unroll
      for (int a = 0; a < 4; ++a)
        af[a] = *(const s16x8*)(&As[ch][a * 16 + c16][quad * 8]);
#pragma unroll
      for (int b = 0; b < 4; ++b)
        bfr[b] = *(const s16x8*)(Bs + (wave * 64 + b * 16 + c16) * BK + quad * 8);
#pragma unroll
      for (int a = 0; a < 4; ++a)
#pragma unroll
        for (int b = 0; b < 4; ++b)
          acc[a][b] = __builtin_amdgcn_mfma_f32_16x16x32_bf16(af[a], bfr[b],
                                                              acc[a][b], 0, 0, 0);
    }

    // Fold this j-tile into register row sums (no atomics, no materialization).
#pragma unroll
    for (int a = 0; a < 4; ++a) {
#pragma unroll
      for (int r = 0; r < 4; ++r) {
        const int gi = i0 + a * 16 + quad * 4 + r;
        const int li = li16[a * 4 + r];
        float ps = 0.0f, ns = 0.0f;
#pragma unroll
        for (int b = 0; b < 4; ++b) {
          const float g = acc[a][b][r];
          const float sv = fmaf(g, 5.0f, C0);
          const float ev = __expf(sv);
          const bool same = (li == lj[b]);
          ps += (same && gi != gj[b]) ? sv : 0.0f;
          ns += same ? 0.0f : ev;
        }
        ps16[a * 4 + r] += ps;
        ns16[a * 4 + r] += ns;
      }
    }
  }

  // ---- Block epilogue: reduce per-lane sums -> 64 rows, 2 atomics each.
  __syncthreads();                 // sweep done; Bs reusable as scratch
  float* rp = (float*)Bs;          // 64 floats
  float* rn = rp + 64;
  if (tid < 128) rp[tid] = 0.0f;   // zeros rp[0..63] and rn[0..63]
  __syncthreads();
#pragma unroll
  for (int a = 0; a < 4; ++a) {
#pragma unroll
    for (int r = 0; r < 4; ++r) {
      float ps = ps16[a * 4 + r], ns = ns16[a * 4 + r];
#pragma unroll
      for (int m = 1; m < 16; m <<= 1) {  // reduce across the 16 c16 lanes
        ps += __shfl_xor(ps, m);
        ns += __shfl_xor(ns, m);
      }
      if (c16 == 0) {  // 4-way wave contention, once per block: trivial
        atomicAdd(&rp[a * 16 + quad * 4 + r], ps);
        atomicAdd(&rn[a * 16 + quad * 4 + r], ns);
      }
    }
  }
  __syncthreads();
  if (tid < 64) {
    atomicAdd(&row_pos[i0 + tid], rp[tid]);   // 8 adds per address chip-wide
    atomicAdd(&row_neg[i0 + tid], rn[tid]);
  }
}

__global__ void __launch_bounds__(512) k_final(
    const float* __restrict__ row_pos, const float* __restrict__ row_neg,
    const int* __restrict__ labels, const int* __restrict__ cnt,
    float* __restrict__ out) {
  __shared__ float ssum[8];
  __shared__ float scnt[8];
  const int tid = threadIdx.x;
  float lsum = 0.0f, lcnt = 0.0f;
  for (int i = tid; i < NROW; i += 512) {
    const float c = (float)(cnt[labels[i]] - 1);
    const float pos = row_pos[i] / (c + 1e-8f);
    const float loss = -pos + logf(row_neg[i] + 1e-8f);
    if (loss > 0.0f) { lsum += loss; lcnt += 1.0f; }
  }
#pragma unroll
  for (int m = 1; m < 64; m <<= 1) {
    lsum += __shfl_xor(lsum, m);
    lcnt += __shfl_xor(lcnt, m);
  }
  if ((tid & 63) == 0) { ssum[tid >> 6] = lsum; scnt[tid >> 6] = lcnt; }
  __syncthreads();
  if (tid == 0) {
    float S = 0.0f, C = 0.0f;
#pragma unroll
    for (int w = 0; w < 8; ++w) { S += ssum[w]; C += scnt[w]; }
    out[0] = S / (C + 1e-8f);
  }
}

extern "C" void kernel_launch(void* const* d_in, const int* in_sizes, int n_in,
                              void* d_out, int out_size, void* d_ws, size_t ws_size,
                              hipStream_t stream) {
  const float* reps = (const float*)d_in[0];
  const int* labels = (const int*)d_in[1];
  float* out = (float*)d_out;
  char* ws = (char*)d_ws;
  // ws layout: Rb (bf16 normalized reps, 8 MiB) | row_pos | row_neg | cnt
  unsigned short* Rb = (unsigned short*)ws;
  float* row_pos = (float*)(ws + (size_t)NROW * DDIM * 2);
  float* row_neg = row_pos + NROW;
  int* cnt = (int*)(row_neg + NROW);

  // row_pos | row_neg | cnt are contiguous: one async memset zeroes all three.
  (void)hipMemsetAsync(row_pos, 0, (size_t)(2 * NROW + NCLS) * 4, stream);
  k_prep<<<NROW / 4, 256, 0, stream>>>(reps, labels, Rb, cnt);
  k_row<<<512, 256, 0, stream>>>(Rb, labels, row_pos, row_neg);
  k_final<<<1, 512, 0, stream>>>(row_pos, row_neg, labels, cnt, out);
  (void)in_sizes; (void)n_in; (void)out_size; (void)ws_size;
}